// Round 5
// baseline (121.558 us; speedup 1.0000x reference)
//
#include <hip/hip_runtime.h>

// AnnularDilatedKNN: B=4, N=4096, C=64, SAMPLE=16, DILATED_RATE=2, r^2=256.
// Round 5: 4 pts/wave (r4) + 2-chunk unroll w/ wrap-around prefetch (r3),
// query and gather SPLIT into separate kernels for per-dispatch diagnostics.
// Numerics bit-match numpy: contract off, sq=(x*x+y*y)+z*z,
// dot=(xi*xj+yi*yj)+zi*zj, d2=(sqi+sqj)-2*dot.

#define BB 4
#define NN 4096
#define KK 16
#define NPB 16                  // points per block (4 waves x 4 pts)
#define NC (NN / 64)            // 64 chunks
#define PLANE (NN * KK)         // 65536

// ---------- K1: P[b*N+j] = (x, y, z, sq) ----------
__global__ __launch_bounds__(256)
void build_soa(const float* __restrict__ xyz, float4* __restrict__ P)
{
#pragma clang fp contract(off)
    const int g = blockIdx.x * 256 + threadIdx.x;      // 0..16383
    const float x = xyz[3 * g], y = xyz[3 * g + 1], z = xyz[3 * g + 2];
    const float sq = (x * x + y * y) + z * z;
    P[g] = make_float4(x, y, z, sq);
}

// ---------- K2: ball query, 4 pts/wave, unroll x2 + prefetch ----------
__global__ __launch_bounds__(256, 4)
void ball_query(const float4* __restrict__ P, int* __restrict__ ids)
{
#pragma clang fp contract(off)
    __shared__ int sids[NPB * KK];

    const int beta = blockIdx.x;            // 0..1023
    const int b    = beta >> 8;
    const int i0   = (beta & 255) * NPB;
    const int t    = threadIdx.x;
    const int lane = t & 63;
    const int wave = t >> 6;

    const float4* Pb = P + (b << 12);
    const int pl0 = wave * 4;

    float4 pi[4];
#pragma unroll
    for (int p = 0; p < 4; ++p) pi[p] = Pb[i0 + pl0 + p];

    const unsigned long long lt = (1ULL << lane) - 1ULL;
    int cnt[4] = {0, 0, 0, 0};             // wave-uniform
    int h0[4]  = {0, 0, 0, 0};
    int* srow = sids + pl0 * KK;

    // prefetch first two chunks
    float4 cur0 = Pb[lane];
    float4 cur1 = Pb[64 + lane];

    for (int jc = 0; jc < NC; jc += 2) {
        const float4 a = cur0;
        const float4 c = cur1;
        // branch-free wrap-around prefetch (extra loads at the tail are unused)
        cur0 = Pb[(((jc + 2) & (NC - 1)) << 6) + lane];
        cur1 = Pb[(((jc + 3) & (NC - 1)) << 6) + lane];

        const int j0 = (jc << 6) + lane;
        const int j1 = j0 + 64;

#pragma unroll
        for (int p = 0; p < 4; ++p) {
            const float dot = (pi[p].x * a.x + pi[p].y * a.y) + pi[p].z * a.z;
            const float d2  = (pi[p].w + a.w) - 2.0f * dot;
            const bool hq   = d2 < 256.0f;
            const unsigned long long m = __ballot(hq);
            if (m) {
                if (cnt[p] == 0) h0[p] = (jc << 6) + (int)__builtin_ctzll(m);
                const int r = cnt[p] + __popcll(m & lt);
                if (hq && r >= 16 && r <= 30) srow[p * KK + r - 15] = j0;
                cnt[p] += __popcll(m);
            }
        }
#pragma unroll
        for (int p = 0; p < 4; ++p) {
            const float dot = (pi[p].x * c.x + pi[p].y * c.y) + pi[p].z * c.z;
            const float d2  = (pi[p].w + c.w) - 2.0f * dot;
            const bool hq   = d2 < 256.0f;
            const unsigned long long m = __ballot(hq);
            if (m) {
                if (cnt[p] == 0) h0[p] = ((jc + 1) << 6) + (int)__builtin_ctzll(m);
                const int r = cnt[p] + __popcll(m & lt);
                if (hq && r >= 16 && r <= 30) srow[p * KK + r - 15] = j1;
                cnt[p] += __popcll(m);
            }
        }

        const int c01 = cnt[0] < cnt[1] ? cnt[0] : cnt[1];
        const int c23 = cnt[2] < cnt[3] ? cnt[2] : cnt[3];
        if ((c01 < c23 ? c01 : c23) >= 31) break;
    }

    // slot 0 + padding (slots above the last recorded rank) <- first hit
    if (lane < KK) {
#pragma unroll
        for (int p = 0; p < 4; ++p) {
            const int hi = (cnt[p] < 31 ? cnt[p] : 31) - 16;
            if (lane == 0 || lane > hi) srow[p * KK + lane] = h0[p];
        }
    }
    __syncthreads();

    ids[beta * (NPB * KK) + t] = sids[t];   // coalesced block row out
}

// ---------- K3: gather + coalesced write-out ----------
__global__ __launch_bounds__(256)
void gather_out(const float4* __restrict__ P, const float* __restrict__ feat,
                const int* __restrict__ ids, float* __restrict__ out)
{
    const int beta = blockIdx.x;
    const int b    = beta >> 8;
    const int i0   = (beta & 255) * NPB;
    const int t    = threadIdx.x;
    const int id   = ids[beta * (NPB * KK) + t];
    const int ob   = i0 * KK + t;           // offset inside each [N*K] plane

    const float4 p = P[(b << 12) + id];
    float* o0 = out + (size_t)b * 3 * PLANE + ob;
    o0[0]         = p.x;
    o0[PLANE]     = p.y;
    o0[2 * PLANE] = p.z;

    const float4* frow = reinterpret_cast<const float4*>(feat + ((size_t)(b << 12) + id) * 64);
    float* o1 = out + (size_t)BB * 3 * PLANE + (size_t)b * 64 * PLANE + ob;
#pragma unroll
    for (int q = 0; q < 16; ++q) {
        const float4 v = frow[q];
        float* oc = o1 + (size_t)(4 * q) * PLANE;
        oc[0]         = v.x;
        oc[PLANE]     = v.y;
        oc[2 * PLANE] = v.z;
        oc[3 * PLANE] = v.w;
    }
}

extern "C" void kernel_launch(void* const* d_in, const int* in_sizes, int n_in,
                              void* d_out, int out_size, void* d_ws, size_t ws_size,
                              hipStream_t stream) {
    const float* xyz  = (const float*)d_in[0];
    const float* feat = (const float*)d_in[1];
    float* out = (float*)d_out;

    float4* P   = (float4*)d_ws;                                // 256 KB
    int*    ids = (int*)((char*)d_ws + (size_t)BB * NN * 16);   // 1 MB

    build_soa <<<BB * NN / 256, 256, 0, stream>>>(xyz, P);
    ball_query<<<BB * NN / NPB, 256, 0, stream>>>(P, ids);      // 1024 blocks
    gather_out<<<BB * NN / NPB, 256, 0, stream>>>(P, feat, ids, out);
}